// Round 4
// baseline (516.488 us; speedup 1.0000x reference)
//
#include <hip/hip_runtime.h>
#include <hip/hip_bf16.h>
#include <math.h>

#define NPIX 2304
#define CCH  128
#define NH   4
#define HC   32
#define NCL  16
#define NBLK 72                          // pixel blocks of 32 for centers
#define KSPLIT 8
#define KEYS 288                         // NPIX / KSPLIT
#define NSTEP 9                          // KEYS / 32
// q pre-scale: log2(e)/sqrt(32) (folds exp->exp2 into q)
#define QSCALE 0.25503489f
#define PPT  16
#define GRID 512                         // == guaranteed co-resident capacity (2 blocks/CU x 256 CU)

typedef __attribute__((ext_vector_type(8))) short short8;
typedef __attribute__((ext_vector_type(4))) float f32x4;

#if __has_builtin(__builtin_amdgcn_exp2f)
#define EXP2(x) __builtin_amdgcn_exp2f(x)
#else
#define EXP2(x) __expf((x) * 0.6931471805599453f)
#endif

static __device__ __forceinline__ short f2bf(float x) {
    __hip_bfloat16 b = __float2bfloat16(x);
    return *reinterpret_cast<short*>(&b);
}

struct KParams {
    const float *xq, *xk, *xv, *pc;
    const int   *labels;
    const float *wq, *bq, *wk, *bk, *wv, *bv;
    const float *w1a, *b1a, *w1b, *b1b, *w2a, *b2a, *w2b, *b2b;
    float *kbuf, *vbuf, *cpart, *denpart, *part_o, *part_l, *rs1, *outp;
    short *qbf, *kbf, *vbfT, *cbf;
    int   *bar;                           // 7 counters, 64B apart, memset to 0 per launch
};

// Manual grid barrier: no cooperative-launch dependency, graph-capture safe.
// Counters start at 0 (hipMemsetAsync before launch). All 512 blocks are
// co-resident by construction (launch_bounds(256,2) => VGPR<=128 => 2 blk/CU;
// LDS 51.6KB => 2 blk/CU), so the spin cannot deadlock.
static __device__ __forceinline__ void gbar(int* cnt) {
    __syncthreads();
    if (threadIdx.x == 0) {
        __threadfence();                                   // release: flush this XCD's writes
        __hip_atomic_fetch_add(cnt, 1, __ATOMIC_RELAXED, __HIP_MEMORY_SCOPE_AGENT);
        while (__hip_atomic_load(cnt, __ATOMIC_RELAXED, __HIP_MEMORY_SCOPE_AGENT) < GRID)
            __builtin_amdgcn_s_sleep(2);
        __threadfence();                                   // acquire: invalidate stale lines
    }
    __syncthreads();
}

__global__ void __launch_bounds__(256, 2) fused_kernel(KParams P) {
    // static LDS, sum 51.6 KB -> 2 blocks/CU
    __shared__ float xsP[CCH * PPT];                   // 8 KB   proj stage
    __shared__ float lsC[2 * NCL * CCH];               // 16 KB  centersA partials
    __shared__ int   labC[32];
    __shared__ float dpsC[2 * NCL];
    __shared__ __align__(16) short Pl[NH][16 * 40];    // 5 KB   attn P tile
    __shared__ __align__(16) float aclT[NH][16][16];   // 4 KB   attn center scores
    __shared__ __align__(16) int   labl[KEYS];         // 1.2 KB
    __shared__ float xsM[16 * CCH];                    // 8 KB   mlp_h stage
    __shared__ float hsM[8 * 2 * CCH];                 // 8 KB   mlp_o stage

    const int bid = blockIdx.x;
    const int t   = threadIdx.x;

    // ================= Phase 1: q/k/v projections (verified r1 body) =================
    if (bid < 3 * 144) {
        const int which = bid / 144;
        const int pxblk = bid % 144;
        const int n0    = pxblk * PPT;
        const int c  = t & 127;
        const int ph = t >> 7;                          // px half (wave-uniform)
        const float* x = (which == 0) ? P.xq : (which == 1) ? P.xk : P.xv;
        const float* w = (which == 0) ? P.wq : (which == 1) ? P.wk : P.wv;
        const float* b = (which == 0) ? P.bq : (which == 1) ? P.bk : P.bv;

#pragma unroll
        for (int it = 0; it < 8; ++it) {
            const int flat = it * 256 + t;              // 0..2047
            const int cc = flat >> 4;
            const int p  = flat & 15;
            xsP[flat] = x[cc * NPIX + n0 + p];
        }
        __syncthreads();

        float acc[8];
        const float bb = b[c];
#pragma unroll
        for (int p = 0; p < 8; ++p) acc[p] = bb;

#pragma unroll 4
        for (int in = 0; in < CCH; ++in) {
            const float wv_ = w[in * CCH + c];
            const float4 xa = *(const float4*)(xsP + in * PPT + ph * 8);
            const float4 xb = *(const float4*)(xsP + in * PPT + ph * 8 + 4);
            acc[0] = fmaf(xa.x, wv_, acc[0]); acc[1] = fmaf(xa.y, wv_, acc[1]);
            acc[2] = fmaf(xa.z, wv_, acc[2]); acc[3] = fmaf(xa.w, wv_, acc[3]);
            acc[4] = fmaf(xb.x, wv_, acc[4]); acc[5] = fmaf(xb.y, wv_, acc[5]);
            acc[6] = fmaf(xb.z, wv_, acc[6]); acc[7] = fmaf(xb.w, wv_, acc[7]);
        }

        const int nb = n0 + ph * 8;
        if (which == 0) {
#pragma unroll
            for (int p = 0; p < 8; ++p)
                P.qbf[(size_t)(nb + p) * CCH + c] = f2bf(acc[p] * QSCALE);
        } else if (which == 1) {
#pragma unroll
            for (int p = 0; p < 8; ++p) {
                P.kbuf[(size_t)(nb + p) * CCH + c] = acc[p];
                P.kbf [(size_t)(nb + p) * CCH + c] = f2bf(acc[p]);
            }
        } else {
#pragma unroll
            for (int p = 0; p < 8; ++p) P.vbuf[(size_t)(nb + p) * CCH + c] = acc[p];
            short8 s0;
#pragma unroll
            for (int p = 0; p < 8; ++p) s0[p] = f2bf(acc[p]);
            *(short8*)(P.vbfT + (size_t)c * NPIX + nb) = s0;
        }
    }
    gbar(P.bar + 0 * 16);

    // ================= Phase 2: centersA (verified body, 32 px/block) ================
    if (bid < NBLK) {
        const int b = bid;
        const int g = t >> 7, c = t & 127;
        if (t < 32) labC[t] = P.labels[b * 32 + t];
        for (int u = t; u < 2 * NCL * CCH; u += 256) lsC[u] = 0.f;
        __syncthreads();

        const int n0 = b * 32 + g * 16;
        for (int p = 0; p < 16; ++p) {
            const int lab = labC[g * 16 + p];
            lsC[(g * NCL + lab) * CCH + c] += P.kbuf[(size_t)(n0 + p) * CCH + c];
        }
        if (t < 2 * NCL) {
            const int g2 = t >> 4, cl = t & 15;
            int cnt = 0;
            for (int p = 0; p < 16; ++p) cnt += (labC[g2 * 16 + p] == cl) ? 1 : 0;
            dpsC[t] = (float)cnt;
        }
        __syncthreads();
        for (int u = t; u < NCL * CCH; u += 256)
            P.cpart[(size_t)b * NCL * CCH + u] = lsC[u] + lsC[NCL * CCH + u];
        if (t < NCL) P.denpart[b * NCL + t] = dpsC[t] + dpsC[NCL + t];
    }
    gbar(P.bar + 1 * 16);

    // ================= Phase 3: centersB reduce (verified body) ======================
    if (bid < 8) {
        const int idx = bid * 256 + t;                  // 0..2047
        const int kk  = idx >> 7;
        float den = 0.f;
        for (int b = 0; b < NBLK; ++b) den += P.denpart[b * NCL + kk];
        float s = 0.f;
        for (int b = 0; b < NBLK; ++b) s += P.cpart[(size_t)b * NCL * CCH + idx];
        P.cbf[idx] = f2bf(s / (den + 1e-6f));
    }
    gbar(P.bar + 2 * 16);

    // ================= Phase 4: MFMA attention (verified r1 body, grid-stride) =======
    {
        const int w    = t >> 6;
        const int lane = t & 63;
        const int quad = lane >> 4;
        const int lq   = lane & 15;

        for (int vb = bid; vb < 144 * KSPLIT; vb += GRID) {
            const int qt = vb >> 3, ks = vb & 7;
            const int i0 = qt * 16, j0 = ks * KEYS;

            __syncthreads();                            // labl WAR across vb iters
            for (int u = t; u < KEYS / 4; u += 256)
                *(int4*)(labl + u * 4) = *(const int4*)(P.labels + j0 + u * 4);

            const short8 aq = *(const short8*)(P.qbf + (size_t)(i0 + lq) * CCH + w * HC + quad * 8);
            {
                const short8 bc = *(const short8*)(P.cbf + (size_t)lq * CCH + w * HC + quad * 8);
                f32x4 z = {0.f, 0.f, 0.f, 0.f};
                f32x4 acd = __builtin_amdgcn_mfma_f32_16x16x32_bf16(aq, bc, z, 0, 0, 0);
                *(f32x4*)(&aclT[w][lq][quad * 4]) = acd;   // [center][q-row], wave-private
            }
            int labi[4];
#pragma unroll
            for (int r = 0; r < 4; ++r) labi[r] = P.labels[i0 + quad * 4 + r];
            __syncthreads();                            // labl ready

            const short* kp  = P.kbf  + (size_t)(j0 + lq) * CCH + w * HC + quad * 8;
            const short* vp  = P.vbfT + (size_t)(w * HC + lq) * NPIX + j0 + quad * 8;
            const float* pcp = P.pc   + (size_t)(i0 + quad * 4) * NPIX + j0 + lq;

            short8 k0A, k1A, v0A, v1A, k0B, k1B, v0B, v1B;
            float pcA[8], pcB[8];
            f32x4 accO0 = {0.f, 0.f, 0.f, 0.f};
            f32x4 accO1 = {0.f, 0.f, 0.f, 0.f};
            float lp[4] = {0.f, 0.f, 0.f, 0.f};

#define ISSUE(K0_, K1_, V0_, V1_, s) do {                                         \
        K0_ = *(const short8*)(kp + (size_t)(s) * 32 * CCH);                      \
        K1_ = *(const short8*)(kp + (size_t)((s) * 32 + 16) * CCH);               \
        V0_ = *(const short8*)(vp + (s) * 32);                                    \
        V1_ = *(const short8*)(vp + (size_t)16 * NPIX + (s) * 32);                \
    } while (0)

#define ISSUE_PC(dst, s) do {                                                     \
        _Pragma("unroll")                                                         \
        for (int r_ = 0; r_ < 4; ++r_) {                                          \
            dst[r_ * 2 + 0] = pcp[(size_t)r_ * NPIX + (s) * 32];                  \
            dst[r_ * 2 + 1] = pcp[(size_t)r_ * NPIX + (s) * 32 + 16];             \
        }                                                                         \
    } while (0)

#define COMPUTE(s, K0_, K1_, V0_, V1_, PCUSE) do {                                \
        _Pragma("unroll")                                                         \
        for (int kh = 0; kh < 2; ++kh) {                                          \
            const short8 bk = (kh == 0) ? K0_ : K1_;                              \
            f32x4 z = {0.f, 0.f, 0.f, 0.f};                                       \
            const f32x4 sv = __builtin_amdgcn_mfma_f32_16x16x32_bf16(aq, bk, z, 0, 0, 0);\
            const int slab = labl[(s) * 32 + kh * 16 + lq];                       \
            const f32x4 av4 = *(const f32x4*)(&aclT[w][slab][quad * 4]);          \
            _Pragma("unroll")                                                     \
            for (int r = 0; r < 4; ++r) {                                         \
                const float sc_ = (slab == labi[r]) ? sv[r] : av4[r] * PCUSE[r * 2 + kh];\
                const float p   = EXP2(sc_);                                      \
                lp[r] += p;                                                       \
                Pl[w][(quad * 4 + r) * 40 + kh * 16 + lq] = f2bf(p);              \
            }                                                                     \
        }                                                                         \
        const short8 ap = *(const short8*)(&Pl[w][lq * 40 + quad * 8]);           \
        accO0 = __builtin_amdgcn_mfma_f32_16x16x32_bf16(ap, V0_, accO0, 0, 0, 0); \
        accO1 = __builtin_amdgcn_mfma_f32_16x16x32_bf16(ap, V1_, accO1, 0, 0, 0); \
    } while (0)

            ISSUE(k0A, k1A, v0A, v1A, 0);
            ISSUE_PC(pcA, 0);
            for (int sb = 0; sb < NSTEP; sb += 2) {
                if (sb + 1 < NSTEP) { ISSUE(k0B, k1B, v0B, v1B, sb + 1); ISSUE_PC(pcB, sb + 1); }
                COMPUTE(sb, k0A, k1A, v0A, v1A, pcA);
                if (sb + 1 < NSTEP) {
                    if (sb + 2 < NSTEP) { ISSUE(k0A, k1A, v0A, v1A, sb + 2); ISSUE_PC(pcA, sb + 2); }
                    COMPUTE(sb + 1, k0B, k1B, v0B, v1B, pcB);
                }
            }
#undef ISSUE
#undef ISSUE_PC
#undef COMPUTE

#pragma unroll
            for (int r = 0; r < 4; ++r) {
                float v = lp[r];
                v += __shfl_xor(v, 1, 64);
                v += __shfl_xor(v, 2, 64);
                v += __shfl_xor(v, 4, 64);
                v += __shfl_xor(v, 8, 64);
                lp[r] = v;
            }
            if (lq == 0) {
#pragma unroll
                for (int r = 0; r < 4; ++r)
                    P.part_l[((size_t)ks * NPIX + i0 + quad * 4 + r) * NH + w] = lp[r];
            }
#pragma unroll
            for (int r = 0; r < 4; ++r) {
                float* po = P.part_o + ((size_t)ks * NPIX + i0 + quad * 4 + r) * CCH + w * HC;
                po[lq]      = accO0[r];
                po[16 + lq] = accO1[r];
            }
        }
    }
    gbar(P.bar + 3 * 16);

    // ================= Phase 5/7: MLP hidden (verified r1 body, grid-stride) =========
#define MLP_H(MODE, XIN, WA, BA, HOUT)                                             \
    for (int vb = bid; vb < 144 * 4; vb += GRID) {                                 \
        const int nb_ = vb % 144, hb_ = vb / 144;                                  \
        const int n0 = nb_ * 16;                                                   \
        __syncthreads();                        /* xsM WAR */                      \
        if (MODE == 0) {                                                           \
            for (int u = t; u < 512; u += 256) {                                   \
                const int p = u >> 5, c4 = (u & 31) * 4;                           \
                const int hh2 = c4 >> 5;                                           \
                float ls_ = 0.f;                                                   \
                _Pragma("unroll")                                                  \
                for (int ks = 0; ks < KSPLIT; ++ks)                                \
                    ls_ += P.part_l[((size_t)ks * NPIX + n0 + p) * NH + hh2];      \
                float sx = 0.f, sy = 0.f, sz = 0.f, sw2 = 0.f;                     \
                _Pragma("unroll")                                                  \
                for (int ks = 0; ks < KSPLIT; ++ks) {                              \
                    const float4 v = *(const float4*)(P.part_o + ((size_t)ks * NPIX + n0 + p) * CCH + c4);\
                    sx += v.x; sy += v.y; sz += v.z; sw2 += v.w;                   \
                }                                                                  \
                const float inv = 1.f / ls_;                                       \
                xsM[p * CCH + c4 + 0] = sx * inv;                                  \
                xsM[p * CCH + c4 + 1] = sy * inv;                                  \
                xsM[p * CCH + c4 + 2] = sz * inv;                                  \
                xsM[p * CCH + c4 + 3] = sw2 * inv;                                 \
            }                                                                      \
        } else {                                                                   \
            for (int u = t; u < 512; u += 256) {                                   \
                const int p = u >> 5, c4 = (u & 31) * 4;                           \
                *(float4*)(xsM + p * CCH + c4) = *(const float4*)(XIN + (size_t)(n0 + p) * CCH + c4);\
            }                                                                      \
        }                                                                          \
        __syncthreads();                                                           \
        const int hh = hb_ * 64 + (t & 63);                                        \
        const int pg = t >> 6;                                                     \
        float acc[4];                                                              \
        const float bb = BA[hh];                                                   \
        _Pragma("unroll")                                                          \
        for (int p = 0; p < 4; ++p) acc[p] = bb;                                   \
        for (int it = 0; it < CCH / 8; ++it) {                                     \
            float wr[8];                                                           \
            _Pragma("unroll")                                                      \
            for (int k = 0; k < 8; ++k) wr[k] = WA[(it * 8 + k) * 2 * CCH + hh];   \
            _Pragma("unroll")                                                      \
            for (int p = 0; p < 4; ++p) {                                          \
                const float4 xa = *(const float4*)(xsM + (pg * 4 + p) * CCH + it * 8);\
                const float4 xb = *(const float4*)(xsM + (pg * 4 + p) * CCH + it * 8 + 4);\
                acc[p] = fmaf(xa.x, wr[0], acc[p]); acc[p] = fmaf(xa.y, wr[1], acc[p]);\
                acc[p] = fmaf(xa.z, wr[2], acc[p]); acc[p] = fmaf(xa.w, wr[3], acc[p]);\
                acc[p] = fmaf(xb.x, wr[4], acc[p]); acc[p] = fmaf(xb.y, wr[5], acc[p]);\
                acc[p] = fmaf(xb.z, wr[6], acc[p]); acc[p] = fmaf(xb.w, wr[7], acc[p]);\
            }                                                                      \
        }                                                                          \
        _Pragma("unroll")                                                          \
        for (int p = 0; p < 4; ++p) {                                              \
            const float v = acc[p];                                                \
            HOUT[(size_t)(n0 + pg * 4 + p) * 2 * CCH + hh] = (v > 0.f) ? v : 0.01f * v;\
        }                                                                          \
    }

    // ================= Phase 6/8: MLP out + residual (verified r1 body) ==============
#define MLP_O(MODE, HIN, WB, BB2, RES, OUTP)                                       \
    for (int vb = bid; vb < 288 * 2; vb += GRID) {                                 \
        const int nb_ = vb % 288, yb_ = vb / 288;                                  \
        const int n0 = nb_ * 8;                                                    \
        __syncthreads();                        /* hsM WAR */                      \
        for (int u = t; u < 512; u += 256) {                                       \
            const int p = u >> 6, c4 = (u & 63) * 4;                               \
            *(float4*)(hsM + p * 2 * CCH + c4) = *(const float4*)(HIN + (size_t)(n0 + p) * 2 * CCH + c4);\
        }                                                                          \
        __syncthreads();                                                           \
        const int c  = yb_ * 64 + (t & 63);                                        \
        const int pg = t >> 6;                                                     \
        const float bb = BB2[c];                                                   \
        float a0 = bb, a1 = bb;                                                    \
        for (int it = 0; it < 2 * CCH / 8; ++it) {                                 \
            float wr[8];                                                           \
            _Pragma("unroll")                                                      \
            for (int k = 0; k < 8; ++k) wr[k] = WB[(it * 8 + k) * CCH + c];        \
            const float4 ha = *(const float4*)(hsM + (pg * 2 + 0) * 2 * CCH + it * 8);\
            const float4 hb = *(const float4*)(hsM + (pg * 2 + 0) * 2 * CCH + it * 8 + 4);\
            a0 = fmaf(ha.x, wr[0], a0); a0 = fmaf(ha.y, wr[1], a0);                \
            a0 = fmaf(ha.z, wr[2], a0); a0 = fmaf(ha.w, wr[3], a0);                \
            a0 = fmaf(hb.x, wr[4], a0); a0 = fmaf(hb.y, wr[5], a0);                \
            a0 = fmaf(hb.z, wr[6], a0); a0 = fmaf(hb.w, wr[7], a0);                \
            const float4 hc = *(const float4*)(hsM + (pg * 2 + 1) * 2 * CCH + it * 8);\
            const float4 hd = *(const float4*)(hsM + (pg * 2 + 1) * 2 * CCH + it * 8 + 4);\
            a1 = fmaf(hc.x, wr[0], a1); a1 = fmaf(hc.y, wr[1], a1);                \
            a1 = fmaf(hc.z, wr[2], a1); a1 = fmaf(hc.w, wr[3], a1);                \
            a1 = fmaf(hd.x, wr[4], a1); a1 = fmaf(hd.y, wr[5], a1);                \
            a1 = fmaf(hd.z, wr[6], a1); a1 = fmaf(hd.w, wr[7], a1);                \
        }                                                                          \
        const int na = n0 + pg * 2, nb2 = na + 1;                                  \
        if (MODE == 0) {                                                           \
            OUTP[(size_t)na * CCH + c]  = RES[(size_t)na * CCH + c] + a0;          \
            OUTP[(size_t)nb2 * CCH + c] = RES[(size_t)nb2 * CCH + c] + a1;         \
        } else {                                                                   \
            OUTP[(size_t)c * NPIX + na]  = RES[(size_t)na * CCH + c] + a0;         \
            OUTP[(size_t)c * NPIX + nb2] = RES[(size_t)nb2 * CCH + c] + a1;        \
        }                                                                          \
    }

    MLP_H(0, P.rs1 /*unused*/, P.w1a, P.b1a, P.rs1 /*h1*/)
    gbar(P.bar + 4 * 16);
    MLP_O(0, P.rs1 /*h1*/, P.w1b, P.b1b, P.vbuf, P.kbuf /*rs1 out*/)
    gbar(P.bar + 5 * 16);
    MLP_H(1, P.kbuf /*rs1*/, P.w2a, P.b2a, P.rs1 /*h2*/)
    gbar(P.bar + 6 * 16);
    MLP_O(1, P.rs1 /*h2*/, P.w2b, P.b2b, P.kbuf /*rs1*/, P.outp)
#undef MLP_H
#undef MLP_O
}
// Buffer aliasing note: h1/h2 need [N][256] floats. We reuse workspace:
//   h (both MLPs)  -> P.rs1 slot, sized [N][2*CCH]
//   rs1 (residual) -> P.kbuf slot ([N][128], kbuf dead after phase 2)
// Dependencies respected: kbuf last read in phase 2; h1 written P5, read P6;
// rs1 written P6, read P7 (xin) and P8 (res); h2 written P7, read P8.

extern "C" void kernel_launch(void* const* d_in, const int* in_sizes, int n_in,
                              void* d_out, int out_size, void* d_ws, size_t ws_size,
                              hipStream_t stream) {
    const float* q_img = (const float*)d_in[0];
    const float* k_img = (const float*)d_in[1];
    const float* v_img = (const float*)d_in[2];
    const float* pc    = (const float*)d_in[3];
    const int*   labels= (const int*)  d_in[4];

    float* fw = (float*)d_ws;
    float* kbuf    = fw;                                  // [N][128] (k, then rs1)
    float* vbuf    = kbuf + (size_t)NPIX * CCH;           // [N][128]
    float* cpart   = vbuf + (size_t)NPIX * CCH;           // [72][16][128]
    float* denpart = cpart + (size_t)NBLK * NCL * CCH;    // [72][16]
    float* part_o  = denpart + NBLK * NCL;                // [KS][N][128]
    float* part_l  = part_o + (size_t)KSPLIT * NPIX * CCH;// [KS][N][4]
    float* hbuf    = part_l + (size_t)KSPLIT * NPIX * NH; // [N][256] (h1/h2)
    short* sw      = (short*)(hbuf + (size_t)NPIX * 2 * CCH);
    short* qbf     = sw;                                  // [N][128] bf16
    short* kbf     = qbf + (size_t)NPIX * CCH;            // [N][128] bf16
    short* vbfT    = kbf + (size_t)NPIX * CCH;            // [128][N] bf16
    short* cbf     = vbfT + (size_t)NPIX * CCH;           // [16][128] bf16
    int*   bar     = (int*)((char*)d_ws + (size_t)32 * 1024 * 1024);  // far past data

    KParams P;
    P.xq = q_img; P.xk = k_img; P.xv = v_img; P.pc = pc; P.labels = labels;
    P.wq = (const float*)d_in[5];  P.bq = (const float*)d_in[6];
    P.wk = (const float*)d_in[7];  P.bk = (const float*)d_in[8];
    P.wv = (const float*)d_in[9];  P.bv = (const float*)d_in[10];
    P.w1a = (const float*)d_in[11]; P.b1a = (const float*)d_in[12];
    P.w1b = (const float*)d_in[13]; P.b1b = (const float*)d_in[14];
    P.w2a = (const float*)d_in[15]; P.b2a = (const float*)d_in[16];
    P.w2b = (const float*)d_in[17]; P.b2b = (const float*)d_in[18];
    P.kbuf = kbuf; P.vbuf = vbuf; P.cpart = cpart; P.denpart = denpart;
    P.part_o = part_o; P.part_l = part_l; P.rs1 = hbuf; P.outp = (float*)d_out;
    P.qbf = qbf; P.kbf = kbf; P.vbfT = vbfT; P.cbf = cbf; P.bar = bar;

    hipMemsetAsync(bar, 0, 512, stream);                  // zero barrier counters
    fused_kernel<<<dim3(GRID), dim3(256), 0, stream>>>(P);
}

// Round 5
// 298.955 us; speedup vs baseline: 1.7276x; 1.7276x over previous
//
#include <hip/hip_runtime.h>
#include <hip/hip_bf16.h>
#include <math.h>

#define NPIX 2304
#define CCH  128
#define NH   4
#define HC   32
#define NCL  16
#define KSPLIT 8
#define KEYS 288
#define NSTEP 9
#define QSCALE 0.25503489f               // log2(e)/sqrt(32)
#define PPT  16
#define GRID 512                          // 2 blocks/CU x 256 CU, forced by 56KB LDS

typedef __attribute__((ext_vector_type(8))) short short8;
typedef __attribute__((ext_vector_type(4))) float f32x4;

#if __has_builtin(__builtin_amdgcn_exp2f)
#define EXP2(x) __builtin_amdgcn_exp2f(x)
#else
#define EXP2(x) __expf((x) * 0.6931471805599453f)
#endif

#define AADD(p, v) __hip_atomic_fetch_add((p), (v), __ATOMIC_RELAXED, __HIP_MEMORY_SCOPE_AGENT)
#define ALOAD(p)   __hip_atomic_load((p), __ATOMIC_RELAXED, __HIP_MEMORY_SCOPE_AGENT)
#define ASTORE(p, v) __hip_atomic_store((p), (v), __ATOMIC_RELAXED, __HIP_MEMORY_SCOPE_AGENT)
#define AXCHG(p, v) __hip_atomic_exchange((p), (v), __ATOMIC_RELAXED, __HIP_MEMORY_SCOPE_AGENT)

static __device__ __forceinline__ short f2bf(float x) {
    __hip_bfloat16 b = __float2bfloat16(x);
    return *reinterpret_cast<short*>(&b);
}

struct KParams {
    const float *xq, *xk, *xv, *pc;
    const int   *labels;
    const float *wq, *bq, *wk, *bk, *wv, *bv;
    const float *w1a, *b1a, *w1b, *b1b, *w2a, *b2a, *w2b, *b2b;
    float *vbuf, *part_o, *part_l, *cpart, *denpart, *cbff, *h1, *h2, *rs1, *outp;
    short *qbf, *kbf, *vbfT;
    int   *bar;
};

// Arrive-only grid barrier (no cache ops): producers wrote via sc0sc1
// write-through stores (MALL-coherent) or consumers are first-touch.
static __device__ __forceinline__ void gbar_arrive(int t, int* cnt) {
    asm volatile("s_waitcnt vmcnt(0)" ::: "memory");
    __syncthreads();
    if (t == 0) {
        AADD(cnt, 1);
        while (ALOAD(cnt) < GRID) __builtin_amdgcn_s_sleep(2);
    }
    __syncthreads();
}

__global__ void __launch_bounds__(256, 2) fused_kernel(KParams P) {
    // 56000B LDS arena: forces exactly 2 blocks/CU (3x56000 > 160KB) so all
    // 512 blocks are co-resident across all 8 XCDs (needed for XCD flush elect).
    __shared__ __align__(16) char arena[56000];
    float* xsP  = (float*)(arena);            // P1: proj stage        8KB
    float* ls2  = (float*)(arena + 8192);     // P1: center partials  16KB
    short* PlA  = (short*)(arena + 24576);    // P2: P tiles           5KB
    float* aclA = (float*)(arena + 29696);    // P2: center scores     4KB
    int*   labl = (int*)  (arena + 33792);    // P2: labels          1.15KB
    float* xsM  = (float*)(arena + 34944);    // P3/5: mlp_h stage     8KB
    float* hsM  = (float*)(arena + 43136);    // P4/6: mlp_o stage     8KB
    float* smls = (float*)(arena + 51328);    // P1: den counts       128B

    const int bid = blockIdx.x;
    const int t   = threadIdx.x;

    int* cntA  = P.bar + 0;
    int* doneA = P.bar + 16;
    int* cbfd  = P.bar + 32;
    int* cntB  = P.bar + 48;
    int* cntC  = P.bar + 320;
    int* cntD  = P.bar + 336;
    int* cntE  = P.bar + 352;
    int* pres  = P.bar + 64;    // + xcd*16
    int* flagA = P.bar + 192;   // + xcd*16

    // register this block's physical XCD (HW_REG_XCC_ID id=20, width 8)
    const int xcd = __builtin_amdgcn_s_getreg(20 | (7 << 11)) & 7;
    if (t == 0) ASTORE(&pres[xcd * 16], 1);

    // ================= Phase 1: q/k/v projections + center partials ===============
    if (bid < 3 * 144) {
        const int which = bid / 144;
        const int pxblk = bid % 144;
        const int n0    = pxblk * PPT;
        const int c  = t & 127;
        const int ph = t >> 7;
        const float* x = (which == 0) ? P.xq : (which == 1) ? P.xk : P.xv;
        const float* w = (which == 0) ? P.wq : (which == 1) ? P.wk : P.wv;
        const float* b = (which == 0) ? P.bq : (which == 1) ? P.bk : P.bv;

#pragma unroll
        for (int it = 0; it < 8; ++it) {
            const int flat = it * 256 + t;
            const int cc = flat >> 4;
            const int p  = flat & 15;
            xsP[flat] = x[cc * NPIX + n0 + p];
        }
        if (which == 1)
            for (int u = t; u < 2 * NCL * CCH; u += 256) ls2[u] = 0.f;
        __syncthreads();

        float acc[8];
        const float bb = b[c];
#pragma unroll
        for (int p = 0; p < 8; ++p) acc[p] = bb;

#pragma unroll 4
        for (int in = 0; in < CCH; ++in) {
            const float wv_ = w[in * CCH + c];
            const float4 xa = *(const float4*)(xsP + in * PPT + ph * 8);
            const float4 xb = *(const float4*)(xsP + in * PPT + ph * 8 + 4);
            acc[0] = fmaf(xa.x, wv_, acc[0]); acc[1] = fmaf(xa.y, wv_, acc[1]);
            acc[2] = fmaf(xa.z, wv_, acc[2]); acc[3] = fmaf(xa.w, wv_, acc[3]);
            acc[4] = fmaf(xb.x, wv_, acc[4]); acc[5] = fmaf(xb.y, wv_, acc[5]);
            acc[6] = fmaf(xb.z, wv_, acc[6]); acc[7] = fmaf(xb.w, wv_, acc[7]);
        }

        const int nb = n0 + ph * 8;
        if (which == 0) {
#pragma unroll
            for (int p = 0; p < 8; ++p)
                P.qbf[(size_t)(nb + p) * CCH + c] = f2bf(acc[p] * QSCALE);
        } else if (which == 1) {
#pragma unroll
            for (int p = 0; p < 8; ++p)
                P.kbf[(size_t)(nb + p) * CCH + c] = f2bf(acc[p]);
            // center partials: thread owns column (ph,c) of ls2 -> race-free
            int lab8[8];
#pragma unroll
            for (int p = 0; p < 8; ++p) lab8[p] = P.labels[nb + p];
#pragma unroll
            for (int p = 0; p < 8; ++p)
                ls2[(ph * NCL + lab8[p]) * CCH + c] += acc[p];
            if (t < 32) {
                const int g2 = t >> 4, cl = t & 15;
                int cnt = 0;
#pragma unroll
                for (int p = 0; p < 8; ++p)
                    cnt += (P.labels[n0 + g2 * 8 + p] == cl) ? 1 : 0;
                smls[t] = (float)cnt;
            }
            __syncthreads();
            for (int u = t; u < NCL * CCH; u += 256)
                ASTORE(&P.cpart[(size_t)pxblk * 2048 + u], ls2[u] + ls2[2048 + u]);
            if (t < 16)
                ASTORE(&P.denpart[pxblk * 16 + t], smls[t] + smls[16 + t]);
        } else {
#pragma unroll
            for (int p = 0; p < 8; ++p) P.vbuf[(size_t)(nb + p) * CCH + c] = acc[p];
            short8 s0;
#pragma unroll
            for (int p = 0; p < 8; ++p) s0[p] = f2bf(acc[p]);
            *(short8*)(P.vbfT + (size_t)c * NPIX + nb) = s0;
        }
    }

    // ========== BARRIER A: arrive + centersB + elected per-XCD L2 flush ==========
    asm volatile("s_waitcnt vmcnt(0)" ::: "memory");
    __syncthreads();
    if (t == 0) {
        AADD(cntA, 1);
        while (ALOAD(cntA) < GRID) __builtin_amdgcn_s_sleep(2);
    }
    __syncthreads();
    if (bid < 8) {   // centersB: cpart/denpart were sc-written -> MALL-fresh
        const int idx = bid * 256 + t, kk = idx >> 7;
        float den = 0.f, s = 0.f;
        for (int b = 0; b < 144; ++b) den += P.denpart[b * 16 + kk];
        for (int b = 0; b < 144; ++b) s   += P.cpart[(size_t)b * 2048 + idx];
        ASTORE(&P.cbff[idx], s / (den + 1e-6f));
        asm volatile("s_waitcnt vmcnt(0)" ::: "memory");
        __syncthreads();
        if (t == 0) AADD(cbfd, 1);
    }
    if (t == 0) {
        int nx = 0;
        for (int i = 0; i < 8; ++i) nx += ALOAD(&pres[i * 16]);
        const int win = (AXCHG(&flagA[xcd * 16], 1) == 0);
        if (win || nx < 8) {   // nx<8 => XCC_ID anomaly => everyone flushes (safe)
            __builtin_amdgcn_fence(__ATOMIC_RELEASE, "agent");   // buffer_wbl2
            AADD(doneA, 1);
        }
        const int tgt = (nx == 8) ? 8 : GRID;
        while (ALOAD(doneA) < tgt) __builtin_amdgcn_s_sleep(2);
        while (ALOAD(cbfd) < 8)    __builtin_amdgcn_s_sleep(2);
    }
    __syncthreads();

    // ================= Phase 2: MFMA attention (r4-verified body) ================
    {
        const int w    = t >> 6;
        const int lane = t & 63;
        const int quad = lane >> 4;
        const int lq   = lane & 15;
        short* PlB  = PlA + w * 640;
        float* aclW = aclA + w * 256;   // [center][row]

        // centers fragment from sc-written f32 centers (tile-invariant)
        short8 bc;
        {
            const float4 c0 = *(const float4*)(P.cbff + lq * CCH + w * HC + quad * 8);
            const float4 c1 = *(const float4*)(P.cbff + lq * CCH + w * HC + quad * 8 + 4);
            bc[0] = f2bf(c0.x); bc[1] = f2bf(c0.y); bc[2] = f2bf(c0.z); bc[3] = f2bf(c0.w);
            bc[4] = f2bf(c1.x); bc[5] = f2bf(c1.y); bc[6] = f2bf(c1.z); bc[7] = f2bf(c1.w);
        }

        for (int vb = bid; vb < 144 * KSPLIT; vb += GRID) {
            const int qt = vb >> 3, ks = vb & 7;
            const int i0 = qt * 16, j0 = ks * KEYS;

            __syncthreads();
            for (int u = t; u < KEYS / 4; u += 256)
                *(int4*)(labl + u * 4) = *(const int4*)(P.labels + j0 + u * 4);

            const short8 aq = *(const short8*)(P.qbf + (size_t)(i0 + lq) * CCH + w * HC + quad * 8);
            {
                f32x4 z = {0.f, 0.f, 0.f, 0.f};
                f32x4 acd = __builtin_amdgcn_mfma_f32_16x16x32_bf16(aq, bc, z, 0, 0, 0);
                *(f32x4*)(aclW + lq * 16 + quad * 4) = acd;
            }
            int labi[4];
#pragma unroll
            for (int r = 0; r < 4; ++r) labi[r] = P.labels[i0 + quad * 4 + r];
            __syncthreads();

            const short* kp  = P.kbf  + (size_t)(j0 + lq) * CCH + w * HC + quad * 8;
            const short* vp  = P.vbfT + (size_t)(w * HC + lq) * NPIX + j0 + quad * 8;
            const float* pcp = P.pc   + (size_t)(i0 + quad * 4) * NPIX + j0 + lq;

            short8 k0A, k1A, v0A, v1A, k0B, k1B, v0B, v1B;
            float pcA[8], pcB[8];
            f32x4 accO0 = {0.f, 0.f, 0.f, 0.f};
            f32x4 accO1 = {0.f, 0.f, 0.f, 0.f};
            float lp[4] = {0.f, 0.f, 0.f, 0.f};

#define ISSUE(K0_, K1_, V0_, V1_, s) do {                                         \
        K0_ = *(const short8*)(kp + (size_t)(s) * 32 * CCH);                      \
        K1_ = *(const short8*)(kp + (size_t)((s) * 32 + 16) * CCH);               \
        V0_ = *(const short8*)(vp + (s) * 32);                                    \
        V1_ = *(const short8*)(vp + (size_t)16 * NPIX + (s) * 32);                \
    } while (0)

#define ISSUE_PC(dst, s) do {                                                     \
        _Pragma("unroll")                                                         \
        for (int r_ = 0; r_ < 4; ++r_) {                                          \
            dst[r_ * 2 + 0] = pcp[(size_t)r_ * NPIX + (s) * 32];                  \
            dst[r_ * 2 + 1] = pcp[(size_t)r_ * NPIX + (s) * 32 + 16];             \
        }                                                                         \
    } while (0)

#define COMPUTE(s, K0_, K1_, V0_, V1_, PCUSE) do {                                \
        _Pragma("unroll")                                                         \
        for (int kh = 0; kh < 2; ++kh) {                                          \
            const short8 bk = (kh == 0) ? K0_ : K1_;                              \
            f32x4 z = {0.f, 0.f, 0.f, 0.f};                                       \
            const f32x4 sv = __builtin_amdgcn_mfma_f32_16x16x32_bf16(aq, bk, z, 0, 0, 0);\
            const int slab = labl[(s) * 32 + kh * 16 + lq];                       \
            const f32x4 av4 = *(const f32x4*)(aclW + slab * 16 + quad * 4);       \
            _Pragma("unroll")                                                     \
            for (int r = 0; r < 4; ++r) {                                         \
                const float sc_ = (slab == labi[r]) ? sv[r] : av4[r] * PCUSE[r * 2 + kh];\
                const float p   = EXP2(sc_);                                      \
                lp[r] += p;                                                       \
                PlB[(quad * 4 + r) * 40 + kh * 16 + lq] = f2bf(p);                \
            }                                                                     \
        }                                                                         \
        const short8 ap = *(const short8*)(PlB + lq * 40 + quad * 8);             \
        accO0 = __builtin_amdgcn_mfma_f32_16x16x32_bf16(ap, V0_, accO0, 0, 0, 0); \
        accO1 = __builtin_amdgcn_mfma_f32_16x16x32_bf16(ap, V1_, accO1, 0, 0, 0); \
    } while (0)

            ISSUE(k0A, k1A, v0A, v1A, 0);
            ISSUE_PC(pcA, 0);
            for (int sb = 0; sb < NSTEP; sb += 2) {
                if (sb + 1 < NSTEP) { ISSUE(k0B, k1B, v0B, v1B, sb + 1); ISSUE_PC(pcB, sb + 1); }
                COMPUTE(sb, k0A, k1A, v0A, v1A, pcA);
                if (sb + 1 < NSTEP) {
                    if (sb + 2 < NSTEP) { ISSUE(k0A, k1A, v0A, v1A, sb + 2); ISSUE_PC(pcA, sb + 2); }
                    COMPUTE(sb + 1, k0B, k1B, v0B, v1B, pcB);
                }
            }
#undef ISSUE
#undef ISSUE_PC
#undef COMPUTE

#pragma unroll
            for (int r = 0; r < 4; ++r) {
                float v = lp[r];
                v += __shfl_xor(v, 1, 64);
                v += __shfl_xor(v, 2, 64);
                v += __shfl_xor(v, 4, 64);
                v += __shfl_xor(v, 8, 64);
                lp[r] = v;
            }
            if (lq == 0) {
#pragma unroll
                for (int r = 0; r < 4; ++r)
                    ASTORE(&P.part_l[((size_t)ks * NPIX + i0 + quad * 4 + r) * NH + w], lp[r]);
            }
#pragma unroll
            for (int r = 0; r < 4; ++r) {
                float* po = P.part_o + ((size_t)ks * NPIX + i0 + quad * 4 + r) * CCH + w * HC;
                ASTORE(&po[lq],      accO0[r]);
                ASTORE(&po[16 + lq], accO1[r]);
            }
        }
    }
    gbar_arrive(t, cntB);

    // ====== Phases 3-6: MLPs (r4-verified bodies; sc-stores across barriers) =====
#define MLP_H(MODE, XIN, WA, BA, HOUT)                                             \
    for (int vb = bid; vb < 144 * 4; vb += GRID) {                                 \
        const int nb_ = vb % 144, hb_ = vb / 144;                                  \
        const int n0 = nb_ * 16;                                                   \
        __syncthreads();                                                           \
        if (MODE == 0) {                                                           \
            for (int u = t; u < 512; u += 256) {                                   \
                const int p = u >> 5, c4 = (u & 31) * 4;                           \
                const int hh2 = c4 >> 5;                                           \
                float ls_ = 0.f;                                                   \
                _Pragma("unroll")                                                  \
                for (int ks = 0; ks < KSPLIT; ++ks)                                \
                    ls_ += P.part_l[((size_t)ks * NPIX + n0 + p) * NH + hh2];      \
                float sx = 0.f, sy = 0.f, sz = 0.f, sw2 = 0.f;                     \
                _Pragma("unroll")                                                  \
                for (int ks = 0; ks < KSPLIT; ++ks) {                              \
                    const float4 v = *(const float4*)(P.part_o + ((size_t)ks * NPIX + n0 + p) * CCH + c4);\
                    sx += v.x; sy += v.y; sz += v.z; sw2 += v.w;                   \
                }                                                                  \
                const float inv = 1.f / ls_;                                       \
                xsM[p * CCH + c4 + 0] = sx * inv;                                  \
                xsM[p * CCH + c4 + 1] = sy * inv;                                  \
                xsM[p * CCH + c4 + 2] = sz * inv;                                  \
                xsM[p * CCH + c4 + 3] = sw2 * inv;                                 \
            }                                                                      \
        } else {                                                                   \
            for (int u = t; u < 512; u += 256) {                                   \
                const int p = u >> 5, c4 = (u & 31) * 4;                           \
                *(float4*)(xsM + p * CCH + c4) = *(const float4*)(XIN + (size_t)(n0 + p) * CCH + c4);\
            }                                                                      \
        }                                                                          \
        __syncthreads();                                                           \
        const int hh = hb_ * 64 + (t & 63);                                        \
        const int pg = t >> 6;                                                     \
        float acc[4];                                                              \
        const float bb = BA[hh];                                                   \
        _Pragma("unroll")                                                          \
        for (int p = 0; p < 4; ++p) acc[p] = bb;                                   \
        for (int it = 0; it < CCH / 8; ++it) {                                     \
            float wr[8];                                                           \
            _Pragma("unroll")                                                      \
            for (int k = 0; k < 8; ++k) wr[k] = WA[(it * 8 + k) * 2 * CCH + hh];   \
            _Pragma("unroll")                                                      \
            for (int p = 0; p < 4; ++p) {                                          \
                const float4 xa = *(const float4*)(xsM + (pg * 4 + p) * CCH + it * 8);\
                const float4 xb = *(const float4*)(xsM + (pg * 4 + p) * CCH + it * 8 + 4);\
                acc[p] = fmaf(xa.x, wr[0], acc[p]); acc[p] = fmaf(xa.y, wr[1], acc[p]);\
                acc[p] = fmaf(xa.z, wr[2], acc[p]); acc[p] = fmaf(xa.w, wr[3], acc[p]);\
                acc[p] = fmaf(xb.x, wr[4], acc[p]); acc[p] = fmaf(xb.y, wr[5], acc[p]);\
                acc[p] = fmaf(xb.z, wr[6], acc[p]); acc[p] = fmaf(xb.w, wr[7], acc[p]);\
            }                                                                      \
        }                                                                          \
        _Pragma("unroll")                                                          \
        for (int p = 0; p < 4; ++p) {                                              \
            const float v = acc[p];                                                \
            ASTORE(&HOUT[(size_t)(n0 + pg * 4 + p) * 2 * CCH + hh], (v > 0.f) ? v : 0.01f * v);\
        }                                                                          \
    }

#define MLP_O(MODE, HIN, WB, BB2, RES, OUTP)                                       \
    for (int vb = bid; vb < 288 * 2; vb += GRID) {                                 \
        const int nb_ = vb % 288, yb_ = vb / 288;                                  \
        const int n0 = nb_ * 8;                                                    \
        __syncthreads();                                                           \
        for (int u = t; u < 512; u += 256) {                                       \
            const int p = u >> 6, c4 = (u & 63) * 4;                               \
            *(float4*)(hsM + p * 2 * CCH + c4) = *(const float4*)(HIN + (size_t)(n0 + p) * 2 * CCH + c4);\
        }                                                                          \
        __syncthreads();                                                           \
        const int c  = yb_ * 64 + (t & 63);                                        \
        const int pg = t >> 6;                                                     \
        const float bb = BB2[c];                                                   \
        float a0 = bb, a1 = bb;                                                    \
        for (int it = 0; it < 2 * CCH / 8; ++it) {                                 \
            float wr[8];                                                           \
            _Pragma("unroll")                                                      \
            for (int k = 0; k < 8; ++k) wr[k] = WB[(it * 8 + k) * CCH + c];        \
            const float4 ha = *(const float4*)(hsM + (pg * 2 + 0) * 2 * CCH + it * 8);\
            const float4 hb = *(const float4*)(hsM + (pg * 2 + 0) * 2 * CCH + it * 8 + 4);\
            a0 = fmaf(ha.x, wr[0], a0); a0 = fmaf(ha.y, wr[1], a0);                \
            a0 = fmaf(ha.z, wr[2], a0); a0 = fmaf(ha.w, wr[3], a0);                \
            a0 = fmaf(hb.x, wr[4], a0); a0 = fmaf(hb.y, wr[5], a0);                \
            a0 = fmaf(hb.z, wr[6], a0); a0 = fmaf(hb.w, wr[7], a0);                \
            const float4 hc = *(const float4*)(hsM + (pg * 2 + 1) * 2 * CCH + it * 8);\
            const float4 hd = *(const float4*)(hsM + (pg * 2 + 1) * 2 * CCH + it * 8 + 4);\
            a1 = fmaf(hc.x, wr[0], a1); a1 = fmaf(hc.y, wr[1], a1);                \
            a1 = fmaf(hc.z, wr[2], a1); a1 = fmaf(hc.w, wr[3], a1);                \
            a1 = fmaf(hd.x, wr[4], a1); a1 = fmaf(hd.y, wr[5], a1);                \
            a1 = fmaf(hd.z, wr[6], a1); a1 = fmaf(hd.w, wr[7], a1);                \
        }                                                                          \
        const int na = n0 + pg * 2, nb2 = na + 1;                                  \
        if (MODE == 0) {                                                           \
            ASTORE(&OUTP[(size_t)na * CCH + c],  RES[(size_t)na * CCH + c] + a0);  \
            ASTORE(&OUTP[(size_t)nb2 * CCH + c], RES[(size_t)nb2 * CCH + c] + a1); \
        } else {                                                                   \
            OUTP[(size_t)c * NPIX + na]  = RES[(size_t)na * CCH + c] + a0;         \
            OUTP[(size_t)c * NPIX + nb2] = RES[(size_t)nb2 * CCH + c] + a1;        \
        }                                                                          \
    }

    MLP_H(0, P.rs1 /*unused*/, P.w1a, P.b1a, P.h1)
    gbar_arrive(t, cntC);
    MLP_O(0, P.h1, P.w1b, P.b1b, P.vbuf, P.rs1)
    gbar_arrive(t, cntD);
    MLP_H(1, P.rs1, P.w2a, P.b2a, P.h2)
    gbar_arrive(t, cntE);
    MLP_O(1, P.h2, P.w2b, P.b2b, P.rs1, P.outp)
#undef MLP_H
#undef MLP_O
}
// Coherence plan (why arrive-only barriers B-E are safe):
//  - part_o/part_l, cpart/denpart, cbff, h1, h2, rs1: written ONLY via sc0sc1
//    write-through stores (MALL-coherent); readers first-touch them with normal
//    loads => no stale L1/L2 copy can exist. h1 and h2 are SEPARATE buffers.
//  - qbf/kbf/vbfT/vbuf: normal stores in P1, flushed by the elected per-XCD
//    wbl2 at barrier A; never rewritten afterwards.
//  - out: normal stores, flushed by end-of-kernel release.

extern "C" void kernel_launch(void* const* d_in, const int* in_sizes, int n_in,
                              void* d_out, int out_size, void* d_ws, size_t ws_size,
                              hipStream_t stream) {
    float* fw = (float*)d_ws;
    float* vbuf    = fw;                                   // [N][128]
    float* part_o  = vbuf + (size_t)NPIX * CCH;            // [8][N][128]
    float* part_l  = part_o + (size_t)KSPLIT * NPIX * CCH; // [8][N][4]
    float* cpart   = part_l + (size_t)KSPLIT * NPIX * NH;  // [144][2048]
    float* denpart = cpart + (size_t)144 * 2048;           // [144][16]
    float* cbff    = denpart + 144 * 16;                   // [16][128] f32
    float* h1      = cbff + 2048;                          // [N][256]
    float* h2      = h1 + (size_t)NPIX * 2 * CCH;          // [N][256]
    float* rs1     = h2 + (size_t)NPIX * 2 * CCH;          // [N][128]
    short* qbf     = (short*)(rs1 + (size_t)NPIX * CCH);   // [N][128] bf16
    short* kbf     = qbf + (size_t)NPIX * CCH;             // [N][128] bf16
    short* vbfT    = kbf + (size_t)NPIX * CCH;             // [128][N] bf16
    int*   bar     = (int*)((char*)d_ws + (size_t)32 * 1024 * 1024);

    KParams P;
    P.xq = (const float*)d_in[0]; P.xk = (const float*)d_in[1];
    P.xv = (const float*)d_in[2]; P.pc = (const float*)d_in[3];
    P.labels = (const int*)d_in[4];
    P.wq = (const float*)d_in[5];  P.bq = (const float*)d_in[6];
    P.wk = (const float*)d_in[7];  P.bk = (const float*)d_in[8];
    P.wv = (const float*)d_in[9];  P.bv = (const float*)d_in[10];
    P.w1a = (const float*)d_in[11]; P.b1a = (const float*)d_in[12];
    P.w1b = (const float*)d_in[13]; P.b1b = (const float*)d_in[14];
    P.w2a = (const float*)d_in[15]; P.b2a = (const float*)d_in[16];
    P.w2b = (const float*)d_in[17]; P.b2b = (const float*)d_in[18];
    P.vbuf = vbuf; P.part_o = part_o; P.part_l = part_l;
    P.cpart = cpart; P.denpart = denpart; P.cbff = cbff;
    P.h1 = h1; P.h2 = h2; P.rs1 = rs1; P.outp = (float*)d_out;
    P.qbf = qbf; P.kbf = kbf; P.vbfT = vbfT; P.bar = bar;

    hipMemsetAsync(bar, 0, 4096, stream);
    fused_kernel<<<dim3(GRID), dim3(256), 0, stream>>>(P);
}

// Round 6
// 229.931 us; speedup vs baseline: 2.2463x; 1.3002x over previous
//
#include <hip/hip_runtime.h>
#include <hip/hip_bf16.h>
#include <math.h>

#define NPIX 2304
#define CCH  128
#define NH   4
#define HC   32
#define NCL  16
#define KSPLIT 8
#define KEYS 288
#define NSTEP 9
#define QSCALE 0.25503489f               // log2(e)/sqrt(32)
#define PPT  16
#define GRID 512                          // 2 blocks/CU x 256 CU, forced by 56KB LDS

typedef __attribute__((ext_vector_type(8))) short short8;
typedef __attribute__((ext_vector_type(4))) float f32x4;

#if __has_builtin(__builtin_amdgcn_exp2f)
#define EXP2(x) __builtin_amdgcn_exp2f(x)
#else
#define EXP2(x) __expf((x) * 0.6931471805599453f)
#endif

#define AADD(p, v) __hip_atomic_fetch_add((p), (v), __ATOMIC_RELAXED, __HIP_MEMORY_SCOPE_AGENT)
#define ALOAD(p)   __hip_atomic_load((p), __ATOMIC_RELAXED, __HIP_MEMORY_SCOPE_AGENT)
#define ASTORE(p, v) __hip_atomic_store((p), (v), __ATOMIC_RELAXED, __HIP_MEMORY_SCOPE_AGENT)
#define AXCHG(p, v) __hip_atomic_exchange((p), (v), __ATOMIC_RELAXED, __HIP_MEMORY_SCOPE_AGENT)

static __device__ __forceinline__ short f2bf(float x) {
    __hip_bfloat16 b = __float2bfloat16(x);
    return *reinterpret_cast<short*>(&b);
}

struct KParams {
    const float *xq, *xk, *xv, *pc;
    const int   *labels;
    const float *wq, *bq, *wk, *bk, *wv, *bv;
    const float *w1a, *b1a, *w1b, *b1b, *w2a, *b2a, *w2b, *b2b;
    float *vbuf, *part_o, *part_l, *cpart, *denpart, *cbff, *outp;
    short *qbf, *kbf, *vbfT;
    int   *bar;
};

__global__ void __launch_bounds__(256, 2) fused_kernel(KParams P) {
    // 56000B LDS arena: forces exactly 2 blocks/CU (3x56000 > 160KB) so all
    // 512 blocks are co-resident across all 8 XCDs (needed for XCD flush elect).
    __shared__ __align__(16) char arena[56000];
    float* xsP  = (float*)(arena);            // P1: proj stage        8KB
    float* ls2  = (float*)(arena + 8192);     // P1: center partials  16KB
    short* PlA  = (short*)(arena + 24576);    // P2: P tiles           5KB
    float* aclA = (float*)(arena + 29696);    // P2: center scores     4KB
    int*   labl = (int*)  (arena + 33792);    // P2: labels          1.15KB
    float* smls = (float*)(arena + 51328);    // P1: den counts       128B

    const int bid = blockIdx.x;
    const int t   = threadIdx.x;

    int* cntA  = P.bar + 0;
    int* doneA = P.bar + 16;
    int* cbfd  = P.bar + 32;
    int* cntB  = P.bar + 48;
    int* pres  = P.bar + 64;    // + xcd*16
    int* flagA = P.bar + 192;   // + xcd*16

    // register this block's physical XCD (HW_REG_XCC_ID id=20, width 8)
    const int xcd = __builtin_amdgcn_s_getreg(20 | (7 << 11)) & 7;
    if (t == 0) ASTORE(&pres[xcd * 16], 1);

    // ================= Phase 1: q/k/v projections + center partials ===============
    if (bid < 3 * 144) {
        const int which = bid / 144;
        const int pxblk = bid % 144;
        const int n0    = pxblk * PPT;
        const int c  = t & 127;
        const int ph = t >> 7;
        const float* x = (which == 0) ? P.xq : (which == 1) ? P.xk : P.xv;
        const float* w = (which == 0) ? P.wq : (which == 1) ? P.wk : P.wv;
        const float* b = (which == 0) ? P.bq : (which == 1) ? P.bk : P.bv;

#pragma unroll
        for (int it = 0; it < 8; ++it) {
            const int flat = it * 256 + t;
            const int cc = flat >> 4;
            const int p  = flat & 15;
            xsP[flat] = x[cc * NPIX + n0 + p];
        }
        if (which == 1)
            for (int u = t; u < 2 * NCL * CCH; u += 256) ls2[u] = 0.f;
        __syncthreads();

        float acc[8];
        const float bb = b[c];
#pragma unroll
        for (int p = 0; p < 8; ++p) acc[p] = bb;

#pragma unroll 4
        for (int in = 0; in < CCH; ++in) {
            const float wv_ = w[in * CCH + c];
            const float4 xa = *(const float4*)(xsP + in * PPT + ph * 8);
            const float4 xb = *(const float4*)(xsP + in * PPT + ph * 8 + 4);
            acc[0] = fmaf(xa.x, wv_, acc[0]); acc[1] = fmaf(xa.y, wv_, acc[1]);
            acc[2] = fmaf(xa.z, wv_, acc[2]); acc[3] = fmaf(xa.w, wv_, acc[3]);
            acc[4] = fmaf(xb.x, wv_, acc[4]); acc[5] = fmaf(xb.y, wv_, acc[5]);
            acc[6] = fmaf(xb.z, wv_, acc[6]); acc[7] = fmaf(xb.w, wv_, acc[7]);
        }

        const int nb = n0 + ph * 8;
        if (which == 0) {
#pragma unroll
            for (int p = 0; p < 8; ++p)
                P.qbf[(size_t)(nb + p) * CCH + c] = f2bf(acc[p] * QSCALE);
        } else if (which == 1) {
#pragma unroll
            for (int p = 0; p < 8; ++p)
                P.kbf[(size_t)(nb + p) * CCH + c] = f2bf(acc[p]);
            // center partials: thread owns column (ph,c) of ls2 -> race-free
            int lab8[8];
#pragma unroll
            for (int p = 0; p < 8; ++p) lab8[p] = P.labels[nb + p];
#pragma unroll
            for (int p = 0; p < 8; ++p)
                ls2[(ph * NCL + lab8[p]) * CCH + c] += acc[p];
            if (t < 32) {
                const int g2 = t >> 4, cl = t & 15;
                int cnt = 0;
#pragma unroll
                for (int p = 0; p < 8; ++p)
                    cnt += (P.labels[n0 + g2 * 8 + p] == cl) ? 1 : 0;
                smls[t] = (float)cnt;
            }
            __syncthreads();
            for (int u = t; u < NCL * CCH; u += 256)
                ASTORE(&P.cpart[(size_t)pxblk * 2048 + u], ls2[u] + ls2[2048 + u]);
            if (t < 16)
                ASTORE(&P.denpart[pxblk * 16 + t], smls[t] + smls[16 + t]);
        } else {
#pragma unroll
            for (int p = 0; p < 8; ++p) P.vbuf[(size_t)(nb + p) * CCH + c] = acc[p];
            short8 s0;
#pragma unroll
            for (int p = 0; p < 8; ++p) s0[p] = f2bf(acc[p]);
            *(short8*)(P.vbfT + (size_t)c * NPIX + nb) = s0;
        }
    }

    // ========== BARRIER A: arrive + centersB + elected per-XCD L2 flush ==========
    asm volatile("s_waitcnt vmcnt(0)" ::: "memory");
    __syncthreads();
    if (t == 0) {
        AADD(cntA, 1);
        while (ALOAD(cntA) < GRID) __builtin_amdgcn_s_sleep(2);
    }
    __syncthreads();
    if (bid < 8) {   // centersB: cpart/denpart were sc-written -> MALL-fresh
        const int idx = bid * 256 + t, kk = idx >> 7;
        float den = 0.f, s = 0.f;
        for (int b = 0; b < 144; ++b) den += P.denpart[b * 16 + kk];
        for (int b = 0; b < 144; ++b) s   += P.cpart[(size_t)b * 2048 + idx];
        ASTORE(&P.cbff[idx], s / (den + 1e-6f));
        asm volatile("s_waitcnt vmcnt(0)" ::: "memory");
        __syncthreads();
        if (t == 0) AADD(cbfd, 1);
    }
    if (t == 0) {
        int nx = 0;
        for (int i = 0; i < 8; ++i) nx += ALOAD(&pres[i * 16]);
        const int win = (AXCHG(&flagA[xcd * 16], 1) == 0);
        if (win || nx < 8) {   // nx<8 => XCC_ID anomaly => everyone flushes (safe)
            __builtin_amdgcn_fence(__ATOMIC_RELEASE, "agent");   // buffer_wbl2
            AADD(doneA, 1);
        }
        const int tgt = (nx == 8) ? 8 : GRID;
        while (ALOAD(doneA) < tgt) __builtin_amdgcn_s_sleep(2);
        while (ALOAD(cbfd) < 8)    __builtin_amdgcn_s_sleep(2);
    }
    __syncthreads();

    // ================= Phase 2: MFMA attention (r5-verified body) ================
    {
        const int w    = t >> 6;
        const int lane = t & 63;
        const int quad = lane >> 4;
        const int lq   = lane & 15;
        short* PlB  = PlA + w * 640;
        float* aclW = aclA + w * 256;   // [center][row]

        // centers fragment from sc-written f32 centers (tile-invariant)
        short8 bc;
        {
            const float4 c0 = *(const float4*)(P.cbff + lq * CCH + w * HC + quad * 8);
            const float4 c1 = *(const float4*)(P.cbff + lq * CCH + w * HC + quad * 8 + 4);
            bc[0] = f2bf(c0.x); bc[1] = f2bf(c0.y); bc[2] = f2bf(c0.z); bc[3] = f2bf(c0.w);
            bc[4] = f2bf(c1.x); bc[5] = f2bf(c1.y); bc[6] = f2bf(c1.z); bc[7] = f2bf(c1.w);
        }

        for (int vb = bid; vb < 144 * KSPLIT; vb += GRID) {
            const int qt = vb >> 3, ks = vb & 7;
            const int i0 = qt * 16, j0 = ks * KEYS;

            __syncthreads();
            for (int u = t; u < KEYS / 4; u += 256)
                *(int4*)(labl + u * 4) = *(const int4*)(P.labels + j0 + u * 4);

            const short8 aq = *(const short8*)(P.qbf + (size_t)(i0 + lq) * CCH + w * HC + quad * 8);
            {
                f32x4 z = {0.f, 0.f, 0.f, 0.f};
                f32x4 acd = __builtin_amdgcn_mfma_f32_16x16x32_bf16(aq, bc, z, 0, 0, 0);
                *(f32x4*)(aclW + lq * 16 + quad * 4) = acd;
            }
            int labi[4];
#pragma unroll
            for (int r = 0; r < 4; ++r) labi[r] = P.labels[i0 + quad * 4 + r];
            __syncthreads();

            const short* kp  = P.kbf  + (size_t)(j0 + lq) * CCH + w * HC + quad * 8;
            const short* vp  = P.vbfT + (size_t)(w * HC + lq) * NPIX + j0 + quad * 8;
            const float* pcp = P.pc   + (size_t)(i0 + quad * 4) * NPIX + j0 + lq;

            short8 k0A, k1A, v0A, v1A, k0B, k1B, v0B, v1B;
            float pcA[8], pcB[8];
            f32x4 accO0 = {0.f, 0.f, 0.f, 0.f};
            f32x4 accO1 = {0.f, 0.f, 0.f, 0.f};
            float lp[4] = {0.f, 0.f, 0.f, 0.f};

#define ISSUE(K0_, K1_, V0_, V1_, s) do {                                         \
        K0_ = *(const short8*)(kp + (size_t)(s) * 32 * CCH);                      \
        K1_ = *(const short8*)(kp + (size_t)((s) * 32 + 16) * CCH);               \
        V0_ = *(const short8*)(vp + (s) * 32);                                    \
        V1_ = *(const short8*)(vp + (size_t)16 * NPIX + (s) * 32);                \
    } while (0)

#define ISSUE_PC(dst, s) do {                                                     \
        _Pragma("unroll")                                                         \
        for (int r_ = 0; r_ < 4; ++r_) {                                          \
            dst[r_ * 2 + 0] = pcp[(size_t)r_ * NPIX + (s) * 32];                  \
            dst[r_ * 2 + 1] = pcp[(size_t)r_ * NPIX + (s) * 32 + 16];             \
        }                                                                         \
    } while (0)

#define COMPUTE(s, K0_, K1_, V0_, V1_, PCUSE) do {                                \
        _Pragma("unroll")                                                         \
        for (int kh = 0; kh < 2; ++kh) {                                          \
            const short8 bk = (kh == 0) ? K0_ : K1_;                              \
            f32x4 z = {0.f, 0.f, 0.f, 0.f};                                       \
            const f32x4 sv = __builtin_amdgcn_mfma_f32_16x16x32_bf16(aq, bk, z, 0, 0, 0);\
            const int slab = labl[(s) * 32 + kh * 16 + lq];                       \
            const f32x4 av4 = *(const f32x4*)(aclW + slab * 16 + quad * 4);       \
            _Pragma("unroll")                                                     \
            for (int r = 0; r < 4; ++r) {                                         \
                const float sc_ = (slab == labi[r]) ? sv[r] : av4[r] * PCUSE[r * 2 + kh];\
                const float p   = EXP2(sc_);                                      \
                lp[r] += p;                                                       \
                PlB[(quad * 4 + r) * 40 + kh * 16 + lq] = f2bf(p);                \
            }                                                                     \
        }                                                                         \
        const short8 ap = *(const short8*)(PlB + lq * 40 + quad * 8);             \
        accO0 = __builtin_amdgcn_mfma_f32_16x16x32_bf16(ap, V0_, accO0, 0, 0, 0); \
        accO1 = __builtin_amdgcn_mfma_f32_16x16x32_bf16(ap, V1_, accO1, 0, 0, 0); \
    } while (0)

            ISSUE(k0A, k1A, v0A, v1A, 0);
            ISSUE_PC(pcA, 0);
            for (int sb = 0; sb < NSTEP; sb += 2) {
                if (sb + 1 < NSTEP) { ISSUE(k0B, k1B, v0B, v1B, sb + 1); ISSUE_PC(pcB, sb + 1); }
                COMPUTE(sb, k0A, k1A, v0A, v1A, pcA);
                if (sb + 1 < NSTEP) {
                    if (sb + 2 < NSTEP) { ISSUE(k0A, k1A, v0A, v1A, sb + 2); ISSUE_PC(pcA, sb + 2); }
                    COMPUTE(sb + 1, k0B, k1B, v0B, v1B, pcB);
                }
            }
#undef ISSUE
#undef ISSUE_PC
#undef COMPUTE

#pragma unroll
            for (int r = 0; r < 4; ++r) {
                float v = lp[r];
                v += __shfl_xor(v, 1, 64);
                v += __shfl_xor(v, 2, 64);
                v += __shfl_xor(v, 4, 64);
                v += __shfl_xor(v, 8, 64);
                lp[r] = v;
            }
            if (lq == 0) {
#pragma unroll
                for (int r = 0; r < 4; ++r)
                    ASTORE(&P.part_l[((size_t)ks * NPIX + i0 + quad * 4 + r) * NH + w], lp[r]);
            }
#pragma unroll
            for (int r = 0; r < 4; ++r) {
                float* po = P.part_o + ((size_t)ks * NPIX + i0 + quad * 4 + r) * CCH + w * HC;
                ASTORE(&po[lq],      accO0[r]);
                ASTORE(&po[16 + lq], accO1[r]);
            }
        }
    }

    // ========== BARRIER B: arrive-only (part_o/part_l were sc-written) ==========
    asm volatile("s_waitcnt vmcnt(0)" ::: "memory");
    __syncthreads();
    if (t == 0) {
        AADD(cntB, 1);
        while (ALOAD(cntB) < GRID) __builtin_amdgcn_s_sleep(2);
    }
    __syncthreads();

    // ====== Phase 3: fused per-pixel MLP chain, 8 px/block, block-local only =====
    if (bid < 288) {
        const int n0 = bid * 8;
        float* xs  = (float*)(arena);            // [8][128]  4KB  attn out
        float* hL  = (float*)(arena + 4096);     // [8][256]  8KB  hidden (both MLPs)
        float* r1L = (float*)(arena + 12288);    // [8][128]  4KB  rs1
        float* fT  = (float*)(arena + 16384);    // [128][8]  4KB  final transposed

        // stage: softmax-normalized attention output (reduce over ks splits)
        {
            const int p = t >> 5, c4 = (t & 31) * 4;
            const int hh2 = c4 >> 5;
            float ls_ = 0.f;
#pragma unroll
            for (int ks = 0; ks < KSPLIT; ++ks)
                ls_ += P.part_l[((size_t)ks * NPIX + n0 + p) * NH + hh2];
            float sx = 0.f, sy = 0.f, sz = 0.f, sw2 = 0.f;
#pragma unroll
            for (int ks = 0; ks < KSPLIT; ++ks) {
                const float4 v = *(const float4*)(P.part_o + ((size_t)ks * NPIX + n0 + p) * CCH + c4);
                sx += v.x; sy += v.y; sz += v.z; sw2 += v.w;
            }
            const float inv = 1.f / ls_;
            xs[p * CCH + c4 + 0] = sx * inv;
            xs[p * CCH + c4 + 1] = sy * inv;
            xs[p * CCH + c4 + 2] = sz * inv;
            xs[p * CCH + c4 + 3] = sw2 * inv;
        }
        __syncthreads();

        const int c  = t & 127;
        const int pg = t >> 7;                    // wave-uniform: px pg*4..pg*4+3

        // ---- MLP1 hidden: thread owns hidden unit t for all 8 px ----
        {
            float ha[8];
            const float b1 = P.b1a[t];
#pragma unroll
            for (int p = 0; p < 8; ++p) ha[p] = b1;
            for (int in = 0; in < CCH; in += 4) {
                const float w0 = P.w1a[(in + 0) * 2 * CCH + t];
                const float w1 = P.w1a[(in + 1) * 2 * CCH + t];
                const float w2 = P.w1a[(in + 2) * 2 * CCH + t];
                const float w3 = P.w1a[(in + 3) * 2 * CCH + t];
#pragma unroll
                for (int p = 0; p < 8; ++p) {
                    const float4 xv = *(const float4*)(xs + p * CCH + in);
                    ha[p] = fmaf(xv.x, w0, ha[p]); ha[p] = fmaf(xv.y, w1, ha[p]);
                    ha[p] = fmaf(xv.z, w2, ha[p]); ha[p] = fmaf(xv.w, w3, ha[p]);
                }
            }
#pragma unroll
            for (int p = 0; p < 8; ++p) {
                const float v = ha[p];
                hL[p * 2 * CCH + t] = (v > 0.f) ? v : 0.01f * v;
            }
        }
        __syncthreads();

        // ---- MLP1 out + residual v -> rs1 (LDS) ----
        {
            float oa[4];
            const float bo = P.b1b[c];
#pragma unroll
            for (int j = 0; j < 4; ++j) oa[j] = bo;
            for (int k = 0; k < 2 * CCH; k += 4) {
                const float w0 = P.w1b[(k + 0) * CCH + c];
                const float w1 = P.w1b[(k + 1) * CCH + c];
                const float w2 = P.w1b[(k + 2) * CCH + c];
                const float w3 = P.w1b[(k + 3) * CCH + c];
#pragma unroll
                for (int j = 0; j < 4; ++j) {
                    const float4 hv = *(const float4*)(hL + (pg * 4 + j) * 2 * CCH + k);
                    oa[j] = fmaf(hv.x, w0, oa[j]); oa[j] = fmaf(hv.y, w1, oa[j]);
                    oa[j] = fmaf(hv.z, w2, oa[j]); oa[j] = fmaf(hv.w, w3, oa[j]);
                }
            }
#pragma unroll
            for (int j = 0; j < 4; ++j)
                r1L[(pg * 4 + j) * CCH + c] =
                    P.vbuf[(size_t)(n0 + pg * 4 + j) * CCH + c] + oa[j];
        }
        __syncthreads();

        // ---- MLP2 hidden (reads rs1, overwrites hL) ----
        {
            float ha[8];
            const float b2 = P.b2a[t];
#pragma unroll
            for (int p = 0; p < 8; ++p) ha[p] = b2;
            for (int in = 0; in < CCH; in += 4) {
                const float w0 = P.w2a[(in + 0) * 2 * CCH + t];
                const float w1 = P.w2a[(in + 1) * 2 * CCH + t];
                const float w2 = P.w2a[(in + 2) * 2 * CCH + t];
                const float w3 = P.w2a[(in + 3) * 2 * CCH + t];
#pragma unroll
                for (int p = 0; p < 8; ++p) {
                    const float4 xv = *(const float4*)(r1L + p * CCH + in);
                    ha[p] = fmaf(xv.x, w0, ha[p]); ha[p] = fmaf(xv.y, w1, ha[p]);
                    ha[p] = fmaf(xv.z, w2, ha[p]); ha[p] = fmaf(xv.w, w3, ha[p]);
                }
            }
            __syncthreads();   // hL WAR: all mlp1-out reads done before overwrite
#pragma unroll
            for (int p = 0; p < 8; ++p) {
                const float v = ha[p];
                hL[p * 2 * CCH + t] = (v > 0.f) ? v : 0.01f * v;
            }
        }
        __syncthreads();

        // ---- MLP2 out + residual rs1 -> fT[c][px] ----
        {
            float oa[4];
            const float bo = P.b2b[c];
#pragma unroll
            for (int j = 0; j < 4; ++j) oa[j] = bo;
            for (int k = 0; k < 2 * CCH; k += 4) {
                const float w0 = P.w2b[(k + 0) * CCH + c];
                const float w1 = P.w2b[(k + 1) * CCH + c];
                const float w2 = P.w2b[(k + 2) * CCH + c];
                const float w3 = P.w2b[(k + 3) * CCH + c];
#pragma unroll
                for (int j = 0; j < 4; ++j) {
                    const float4 hv = *(const float4*)(hL + (pg * 4 + j) * 2 * CCH + k);
                    oa[j] = fmaf(hv.x, w0, oa[j]); oa[j] = fmaf(hv.y, w1, oa[j]);
                    oa[j] = fmaf(hv.z, w2, oa[j]); oa[j] = fmaf(hv.w, w3, oa[j]);
                }
            }
#pragma unroll
            for (int j = 0; j < 4; ++j)
                fT[c * 8 + pg * 4 + j] = r1L[(pg * 4 + j) * CCH + c] + oa[j];
        }
        __syncthreads();

        // ---- coalesced final store: out[c][n0..n0+8) as 2 x float4 per row ----
        {
            const int cc = t >> 1, half = t & 1;
            const float4 v = *(const float4*)(fT + cc * 8 + half * 4);
            *(float4*)(P.outp + (size_t)cc * NPIX + n0 + half * 4) = v;
        }
    }
}
// Coherence plan:
//  - part_o/part_l, cpart/denpart, cbff: ONLY sc0sc1 write-through stores
//    (MALL-coherent); readers first-touch with normal loads.
//  - qbf/kbf/vbfT/vbuf: normal stores in P1, flushed by elected per-XCD wbl2
//    at barrier A; never rewritten afterwards.
//  - MLP chain: entirely block-local LDS (no h1/h2/rs1 globals, no barriers).
//  - out: normal stores, flushed by end-of-kernel release.

extern "C" void kernel_launch(void* const* d_in, const int* in_sizes, int n_in,
                              void* d_out, int out_size, void* d_ws, size_t ws_size,
                              hipStream_t stream) {
    float* fw = (float*)d_ws;
    float* vbuf    = fw;                                   // [N][128]
    float* part_o  = vbuf + (size_t)NPIX * CCH;            // [8][N][128]
    float* part_l  = part_o + (size_t)KSPLIT * NPIX * CCH; // [8][N][4]
    float* cpart   = part_l + (size_t)KSPLIT * NPIX * NH;  // [144][2048]
    float* denpart = cpart + (size_t)144 * 2048;           // [144][16]
    float* cbff    = denpart + 144 * 16;                   // [16][128] f32
    short* qbf     = (short*)(cbff + 2048);                // [N][128] bf16
    short* kbf     = qbf + (size_t)NPIX * CCH;             // [N][128] bf16
    short* vbfT    = kbf + (size_t)NPIX * CCH;             // [128][N] bf16
    int*   bar     = (int*)((char*)d_ws + (size_t)32 * 1024 * 1024);

    KParams P;
    P.xq = (const float*)d_in[0]; P.xk = (const float*)d_in[1];
    P.xv = (const float*)d_in[2]; P.pc = (const float*)d_in[3];
    P.labels = (const int*)d_in[4];
    P.wq = (const float*)d_in[5];  P.bq = (const float*)d_in[6];
    P.wk = (const float*)d_in[7];  P.bk = (const float*)d_in[8];
    P.wv = (const float*)d_in[9];  P.bv = (const float*)d_in[10];
    P.w1a = (const float*)d_in[11]; P.b1a = (const float*)d_in[12];
    P.w1b = (const float*)d_in[13]; P.b1b = (const float*)d_in[14];
    P.w2a = (const float*)d_in[15]; P.b2a = (const float*)d_in[16];
    P.w2b = (const float*)d_in[17]; P.b2b = (const float*)d_in[18];
    P.vbuf = vbuf; P.part_o = part_o; P.part_l = part_l;
    P.cpart = cpart; P.denpart = denpart; P.cbff = cbff;
    P.outp = (float*)d_out;
    P.qbf = qbf; P.kbf = kbf; P.vbfT = vbfT; P.bar = bar;

    hipMemsetAsync(bar, 0, 4096, stream);
    fused_kernel<<<dim3(GRID), dim3(256), 0, stream>>>(P);
}

// Round 7
// 181.069 us; speedup vs baseline: 2.8524x; 1.2699x over previous
//
#include <hip/hip_runtime.h>
#include <hip/hip_bf16.h>
#include <math.h>

#define NPIX 2304
#define CCH  128
#define NH   4
#define HC   32
#define NCL  16
#define KSPLIT 8
#define KEYS 288
#define NSTEP 9
#define QSCALE 0.25503489f               // log2(e)/sqrt(32)
#define PPT  16

typedef __attribute__((ext_vector_type(8))) short short8;
typedef __attribute__((ext_vector_type(4))) float f32x4;

#if __has_builtin(__builtin_amdgcn_exp2f)
#define EXP2(x) __builtin_amdgcn_exp2f(x)
#else
#define EXP2(x) __expf((x) * 0.6931471805599453f)
#endif

static __device__ __forceinline__ short f2bf(float x) {
    __hip_bfloat16 b = __float2bfloat16(x);
    return *reinterpret_cast<short*>(&b);
}

// ---------------- Kernel 1: q/k/v projections + centersA partials (r6 body) ----
__global__ void __launch_bounds__(256) proj_kernel(
        const float* __restrict__ xq, const float* __restrict__ xk,
        const float* __restrict__ xv, const int* __restrict__ labels,
        const float* __restrict__ wq, const float* __restrict__ bq,
        const float* __restrict__ wk, const float* __restrict__ bk,
        const float* __restrict__ wv, const float* __restrict__ bv,
        short* __restrict__ qbf, short* __restrict__ kbf,
        float* __restrict__ vbuf, short* __restrict__ vbfT,
        float* __restrict__ cpart, float* __restrict__ denpart) {
    __shared__ float xsP[CCH * PPT];          // 8 KB
    __shared__ float ls2[2 * NCL * CCH];      // 16 KB
    __shared__ float smls[32];
    const int which = blockIdx.y;
    const int pxblk = blockIdx.x;
    const int n0    = pxblk * PPT;
    const int t  = threadIdx.x;
    const int c  = t & 127;
    const int ph = t >> 7;
    const float* x = (which == 0) ? xq : (which == 1) ? xk : xv;
    const float* w = (which == 0) ? wq : (which == 1) ? wk : wv;
    const float* b = (which == 0) ? bq : (which == 1) ? bk : bv;

#pragma unroll
    for (int it = 0; it < 8; ++it) {
        const int flat = it * 256 + t;
        const int cc = flat >> 4;
        const int p  = flat & 15;
        xsP[flat] = x[cc * NPIX + n0 + p];
    }
    if (which == 1)
        for (int u = t; u < 2 * NCL * CCH; u += 256) ls2[u] = 0.f;
    __syncthreads();

    float acc[8];
    const float bb = b[c];
#pragma unroll
    for (int p = 0; p < 8; ++p) acc[p] = bb;

#pragma unroll 4
    for (int in = 0; in < CCH; ++in) {
        const float wv_ = w[in * CCH + c];
        const float4 xa = *(const float4*)(xsP + in * PPT + ph * 8);
        const float4 xb = *(const float4*)(xsP + in * PPT + ph * 8 + 4);
        acc[0] = fmaf(xa.x, wv_, acc[0]); acc[1] = fmaf(xa.y, wv_, acc[1]);
        acc[2] = fmaf(xa.z, wv_, acc[2]); acc[3] = fmaf(xa.w, wv_, acc[3]);
        acc[4] = fmaf(xb.x, wv_, acc[4]); acc[5] = fmaf(xb.y, wv_, acc[5]);
        acc[6] = fmaf(xb.z, wv_, acc[6]); acc[7] = fmaf(xb.w, wv_, acc[7]);
    }

    const int nb = n0 + ph * 8;
    if (which == 0) {
#pragma unroll
        for (int p = 0; p < 8; ++p)
            qbf[(size_t)(nb + p) * CCH + c] = f2bf(acc[p] * QSCALE);
    } else if (which == 1) {
#pragma unroll
        for (int p = 0; p < 8; ++p)
            kbf[(size_t)(nb + p) * CCH + c] = f2bf(acc[p]);
        // center partials: thread owns column (ph,c) of ls2 -> race-free
        int lab8[8];
#pragma unroll
        for (int p = 0; p < 8; ++p) lab8[p] = labels[nb + p];
#pragma unroll
        for (int p = 0; p < 8; ++p)
            ls2[(ph * NCL + lab8[p]) * CCH + c] += acc[p];
        if (t < 32) {
            const int g2 = t >> 4, cl = t & 15;
            int cnt = 0;
#pragma unroll
            for (int p = 0; p < 8; ++p)
                cnt += (labels[n0 + g2 * 8 + p] == cl) ? 1 : 0;
            smls[t] = (float)cnt;
        }
        __syncthreads();
        for (int u = t; u < NCL * CCH; u += 256)
            cpart[(size_t)pxblk * 2048 + u] = ls2[u] + ls2[2048 + u];
        if (t < 16)
            denpart[pxblk * 16 + t] = smls[t] + smls[16 + t];
    } else {
#pragma unroll
        for (int p = 0; p < 8; ++p) vbuf[(size_t)(nb + p) * CCH + c] = acc[p];
        short8 s0;
#pragma unroll
        for (int p = 0; p < 8; ++p) s0[p] = f2bf(acc[p]);
        *(short8*)(vbfT + (size_t)c * NPIX + nb) = s0;
    }
}

// ---------------- Kernel 2: reduce partials -> bf16 centers ----------------
__global__ void centersB_kernel(const float* __restrict__ cpart,
                                const float* __restrict__ denpart,
                                short* __restrict__ cbf) {
    const int idx = blockIdx.x * 256 + threadIdx.x;   // 0..2047
    const int kk  = idx >> 7;
    float den = 0.f, s = 0.f;
    for (int b = 0; b < 144; ++b) den += denpart[b * 16 + kk];
    for (int b = 0; b < 144; ++b) s   += cpart[(size_t)b * 2048 + idx];
    cbf[idx] = f2bf(s / (den + 1e-6f));
}

// ---------------- Kernel 3: MFMA attention (r1-verified barrier-free body) -----
__global__ void __launch_bounds__(256, 4) attn_part_kernel(
        const short* __restrict__ qbf,  const short* __restrict__ kbf,
        const short* __restrict__ vbfT, const short* __restrict__ cbf,
        const int* __restrict__ labels, const float* __restrict__ pc,
        float* __restrict__ part_o, float* __restrict__ part_l) {
    __shared__ __align__(16) short Pl[NH][16 * 40];
    __shared__ __align__(16) float aclT[NH][16][16];
    __shared__ int   labl[KEYS];
    const int qt   = blockIdx.x;
    const int ks   = blockIdx.y;
    const int tid  = threadIdx.x;
    const int w    = tid >> 6;
    const int lane = tid & 63;
    const int quad = lane >> 4;
    const int lq   = lane & 15;
    const int i0   = qt * 16;
    const int j0   = ks * KEYS;

    for (int u = tid; u < KEYS / 4; u += 256)
        *(int4*)(labl + u * 4) = *(const int4*)(labels + j0 + u * 4);

    const short8 aq = *(const short8*)(qbf + (size_t)(i0 + lq) * CCH + w * HC + quad * 8);
    {
        const short8 bc = *(const short8*)(cbf + (size_t)lq * CCH + w * HC + quad * 8);
        f32x4 z = {0.f, 0.f, 0.f, 0.f};
        f32x4 acd = __builtin_amdgcn_mfma_f32_16x16x32_bf16(aq, bc, z, 0, 0, 0);
        *(f32x4*)(&aclT[w][lq][quad * 4]) = acd;   // [center][q-row], wave-private
    }
    int labi[4];
#pragma unroll
    for (int r = 0; r < 4; ++r) labi[r] = labels[i0 + quad * 4 + r];

    __syncthreads();   // labl ready

    const short* kp  = kbf  + (size_t)(j0 + lq) * CCH + w * HC + quad * 8;
    const short* vp  = vbfT + (size_t)(w * HC + lq) * NPIX + j0 + quad * 8;
    const float* pcp = pc   + (size_t)(i0 + quad * 4) * NPIX + j0 + lq;

    short8 k0A, k1A, v0A, v1A, k0B, k1B, v0B, v1B;
    float pcA[8], pcB[8];
    f32x4 accO0 = {0.f, 0.f, 0.f, 0.f};
    f32x4 accO1 = {0.f, 0.f, 0.f, 0.f};
    float lp[4] = {0.f, 0.f, 0.f, 0.f};

#define ISSUE(K0_, K1_, V0_, V1_, s) do {                                         \
        K0_ = *(const short8*)(kp + (size_t)(s) * 32 * CCH);                      \
        K1_ = *(const short8*)(kp + (size_t)((s) * 32 + 16) * CCH);               \
        V0_ = *(const short8*)(vp + (s) * 32);                                    \
        V1_ = *(const short8*)(vp + (size_t)16 * NPIX + (s) * 32);                \
    } while (0)

#define ISSUE_PC(dst, s) do {                                                     \
        _Pragma("unroll")                                                         \
        for (int r_ = 0; r_ < 4; ++r_) {                                          \
            dst[r_ * 2 + 0] = pcp[(size_t)r_ * NPIX + (s) * 32];                  \
            dst[r_ * 2 + 1] = pcp[(size_t)r_ * NPIX + (s) * 32 + 16];             \
        }                                                                         \
    } while (0)

#define COMPUTE(s, K0_, K1_, V0_, V1_, PCUSE) do {                                \
        _Pragma("unroll")                                                         \
        for (int kh = 0; kh < 2; ++kh) {                                          \
            const short8 bk = (kh == 0) ? K0_ : K1_;                              \
            f32x4 z = {0.f, 0.f, 0.f, 0.f};                                       \
            const f32x4 sv = __builtin_amdgcn_mfma_f32_16x16x32_bf16(aq, bk, z, 0, 0, 0);\
            const int slab = labl[(s) * 32 + kh * 16 + lq];                       \
            const f32x4 av4 = *(const f32x4*)(&aclT[w][slab][quad * 4]);          \
            _Pragma("unroll")                                                     \
            for (int r = 0; r < 4; ++r) {                                         \
                const float sc_ = (slab == labi[r]) ? sv[r] : av4[r] * PCUSE[r * 2 + kh];\
                const float p   = EXP2(sc_);                                      \
                lp[r] += p;                                                       \
                Pl[w][(quad * 4 + r) * 40 + kh * 16 + lq] = f2bf(p);              \
            }                                                                     \
        }                                                                         \
        const short8 ap = *(const short8*)(&Pl[w][lq * 40 + quad * 8]);           \
        accO0 = __builtin_amdgcn_mfma_f32_16x16x32_bf16(ap, V0_, accO0, 0, 0, 0); \
        accO1 = __builtin_amdgcn_mfma_f32_16x16x32_bf16(ap, V1_, accO1, 0, 0, 0); \
    } while (0)

    ISSUE(k0A, k1A, v0A, v1A, 0);
    ISSUE_PC(pcA, 0);
    for (int sb = 0; sb < NSTEP; sb += 2) {
        if (sb + 1 < NSTEP) { ISSUE(k0B, k1B, v0B, v1B, sb + 1); ISSUE_PC(pcB, sb + 1); }
        COMPUTE(sb, k0A, k1A, v0A, v1A, pcA);
        if (sb + 1 < NSTEP) {
            if (sb + 2 < NSTEP) { ISSUE(k0A, k1A, v0A, v1A, sb + 2); ISSUE_PC(pcA, sb + 2); }
            COMPUTE(sb + 1, k0B, k1B, v0B, v1B, pcB);
        }
    }
#undef ISSUE
#undef ISSUE_PC
#undef COMPUTE

#pragma unroll
    for (int r = 0; r < 4; ++r) {
        float v = lp[r];
        v += __shfl_xor(v, 1, 64);
        v += __shfl_xor(v, 2, 64);
        v += __shfl_xor(v, 4, 64);
        v += __shfl_xor(v, 8, 64);
        lp[r] = v;
    }
    if (lq == 0) {
#pragma unroll
        for (int r = 0; r < 4; ++r)
            part_l[((size_t)ks * NPIX + i0 + quad * 4 + r) * NH + w] = lp[r];
    }
#pragma unroll
    for (int r = 0; r < 4; ++r) {
        float* po = part_o + ((size_t)ks * NPIX + i0 + quad * 4 + r) * CCH + w * HC;
        po[lq]      = accO0[r];
        po[16 + lq] = accO1[r];
    }
}

// ---------------- Kernel 4: fused per-pixel MLP chain (r6-verified body) -------
// 8 px/block end-to-end: reduce part_o -> mlp1 -> +v -> rs1(LDS) -> mlp2 -> +rs1
// -> transposed [C][N] store. No h1/h2/rs1 global traffic, block-local syncs only.
__global__ void __launch_bounds__(256) mlp_chain_kernel(
        const float* __restrict__ part_o, const float* __restrict__ part_l,
        const float* __restrict__ vbuf,
        const float* __restrict__ w1a, const float* __restrict__ b1a,
        const float* __restrict__ w1b, const float* __restrict__ b1b,
        const float* __restrict__ w2a, const float* __restrict__ b2a,
        const float* __restrict__ w2b, const float* __restrict__ b2b,
        float* __restrict__ outp) {
    __shared__ float xs[8 * CCH];             // 4 KB  attn out
    __shared__ float hL[8 * 2 * CCH];         // 8 KB  hidden (both MLPs)
    __shared__ float r1L[8 * CCH];            // 4 KB  rs1
    __shared__ float fT[CCH * 8];             // 4 KB  final transposed
    const int n0 = blockIdx.x * 8;
    const int t  = threadIdx.x;

    // stage: softmax-normalized attention output (reduce over ks splits)
    {
        const int p = t >> 5, c4 = (t & 31) * 4;
        const int hh2 = c4 >> 5;
        float ls_ = 0.f;
#pragma unroll
        for (int ks = 0; ks < KSPLIT; ++ks)
            ls_ += part_l[((size_t)ks * NPIX + n0 + p) * NH + hh2];
        float sx = 0.f, sy = 0.f, sz = 0.f, sw2 = 0.f;
#pragma unroll
        for (int ks = 0; ks < KSPLIT; ++ks) {
            const float4 v = *(const float4*)(part_o + ((size_t)ks * NPIX + n0 + p) * CCH + c4);
            sx += v.x; sy += v.y; sz += v.z; sw2 += v.w;
        }
        const float inv = 1.f / ls_;
        xs[p * CCH + c4 + 0] = sx * inv;
        xs[p * CCH + c4 + 1] = sy * inv;
        xs[p * CCH + c4 + 2] = sz * inv;
        xs[p * CCH + c4 + 3] = sw2 * inv;
    }
    __syncthreads();

    const int c  = t & 127;
    const int pg = t >> 7;                    // wave-uniform: px pg*4..pg*4+3

    // ---- MLP1 hidden ----
    {
        float ha[8];
        const float b1 = b1a[t];
#pragma unroll
        for (int p = 0; p < 8; ++p) ha[p] = b1;
        for (int in = 0; in < CCH; in += 4) {
            const float w0 = w1a[(in + 0) * 2 * CCH + t];
            const float w1 = w1a[(in + 1) * 2 * CCH + t];
            const float w2 = w1a[(in + 2) * 2 * CCH + t];
            const float w3 = w1a[(in + 3) * 2 * CCH + t];
#pragma unroll
            for (int p = 0; p < 8; ++p) {
                const float4 xv = *(const float4*)(xs + p * CCH + in);
                ha[p] = fmaf(xv.x, w0, ha[p]); ha[p] = fmaf(xv.y, w1, ha[p]);
                ha[p] = fmaf(xv.z, w2, ha[p]); ha[p] = fmaf(xv.w, w3, ha[p]);
            }
        }
#pragma unroll
        for (int p = 0; p < 8; ++p) {
            const float v = ha[p];
            hL[p * 2 * CCH + t] = (v > 0.f) ? v : 0.01f * v;
        }
    }
    __syncthreads();

    // ---- MLP1 out + residual v -> rs1 (LDS) ----
    {
        float oa[4];
        const float bo = b1b[c];
#pragma unroll
        for (int j = 0; j < 4; ++j) oa[j] = bo;
        for (int k = 0; k < 2 * CCH; k += 4) {
            const float w0 = w1b[(k + 0) * CCH + c];
            const float w1 = w1b[(k + 1) * CCH + c];
            const float w2 = w1b[(k + 2) * CCH + c];
            const float w3 = w1b[(k + 3) * CCH + c];
#pragma unroll
            for (int j = 0; j < 4; ++j) {
                const float4 hv = *(const float4*)(hL + (pg * 4 + j) * 2 * CCH + k);
                oa[j] = fmaf(hv.x, w0, oa[j]); oa[j] = fmaf(hv.y, w1, oa[j]);
                oa[j] = fmaf(hv.z, w2, oa[j]); oa[j] = fmaf(hv.w, w3, oa[j]);
            }
        }
#pragma unroll
        for (int j = 0; j < 4; ++j)
            r1L[(pg * 4 + j) * CCH + c] =
                vbuf[(size_t)(n0 + pg * 4 + j) * CCH + c] + oa[j];
    }
    __syncthreads();

    // ---- MLP2 hidden (reads rs1, overwrites hL) ----
    {
        float ha[8];
        const float b2 = b2a[t];
#pragma unroll
        for (int p = 0; p < 8; ++p) ha[p] = b2;
        for (int in = 0; in < CCH; in += 4) {
            const float w0 = w2a[(in + 0) * 2 * CCH + t];
            const float w1 = w2a[(in + 1) * 2 * CCH + t];
            const float w2 = w2a[(in + 2) * 2 * CCH + t];
            const float w3 = w2a[(in + 3) * 2 * CCH + t];
#pragma unroll
            for (int p = 0; p < 8; ++p) {
                const float4 xv = *(const float4*)(r1L + p * CCH + in);
                ha[p] = fmaf(xv.x, w0, ha[p]); ha[p] = fmaf(xv.y, w1, ha[p]);
                ha[p] = fmaf(xv.z, w2, ha[p]); ha[p] = fmaf(xv.w, w3, ha[p]);
            }
        }
        __syncthreads();   // hL WAR
#pragma unroll
        for (int p = 0; p < 8; ++p) {
            const float v = ha[p];
            hL[p * 2 * CCH + t] = (v > 0.f) ? v : 0.01f * v;
        }
    }
    __syncthreads();

    // ---- MLP2 out + residual rs1 -> fT[c][px] ----
    {
        float oa[4];
        const float bo = b2b[c];
#pragma unroll
        for (int j = 0; j < 4; ++j) oa[j] = bo;
        for (int k = 0; k < 2 * CCH; k += 4) {
            const float w0 = w2b[(k + 0) * CCH + c];
            const float w1 = w2b[(k + 1) * CCH + c];
            const float w2 = w2b[(k + 2) * CCH + c];
            const float w3 = w2b[(k + 3) * CCH + c];
#pragma unroll
            for (int j = 0; j < 4; ++j) {
                const float4 hv = *(const float4*)(hL + (pg * 4 + j) * 2 * CCH + k);
                oa[j] = fmaf(hv.x, w0, oa[j]); oa[j] = fmaf(hv.y, w1, oa[j]);
                oa[j] = fmaf(hv.z, w2, oa[j]); oa[j] = fmaf(hv.w, w3, oa[j]);
            }
        }
#pragma unroll
        for (int j = 0; j < 4; ++j)
            fT[c * 8 + pg * 4 + j] = r1L[(pg * 4 + j) * CCH + c] + oa[j];
    }
    __syncthreads();

    // ---- coalesced final store: out[c][n0..n0+8) as 2 x float4 per row ----
    {
        const int cc = t >> 1, half = t & 1;
        const float4 v = *(const float4*)(fT + cc * 8 + half * 4);
        *(float4*)(outp + (size_t)cc * NPIX + n0 + half * 4) = v;
    }
}

extern "C" void kernel_launch(void* const* d_in, const int* in_sizes, int n_in,
                              void* d_out, int out_size, void* d_ws, size_t ws_size,
                              hipStream_t stream) {
    const float* q_img = (const float*)d_in[0];
    const float* k_img = (const float*)d_in[1];
    const float* v_img = (const float*)d_in[2];
    const float* pc    = (const float*)d_in[3];
    const int*   labels= (const int*)  d_in[4];
    const float* wq = (const float*)d_in[5];   const float* bq = (const float*)d_in[6];
    const float* wk = (const float*)d_in[7];   const float* bk = (const float*)d_in[8];
    const float* wv = (const float*)d_in[9];   const float* bv = (const float*)d_in[10];
    const float* w1a = (const float*)d_in[11]; const float* b1a = (const float*)d_in[12];
    const float* w1b = (const float*)d_in[13]; const float* b1b = (const float*)d_in[14];
    const float* w2a = (const float*)d_in[15]; const float* b2a = (const float*)d_in[16];
    const float* w2b = (const float*)d_in[17]; const float* b2b = (const float*)d_in[18];

    float* fw = (float*)d_ws;
    float* vbuf    = fw;                                   // [N][128]
    float* part_o  = vbuf + (size_t)NPIX * CCH;            // [8][N][128]
    float* part_l  = part_o + (size_t)KSPLIT * NPIX * CCH; // [8][N][4]
    float* cpart   = part_l + (size_t)KSPLIT * NPIX * NH;  // [144][2048]
    float* denpart = cpart + (size_t)144 * 2048;           // [144][16]
    short* qbf     = (short*)(denpart + 144 * 16);         // [N][128] bf16
    short* kbf     = qbf + (size_t)NPIX * CCH;             // [N][128] bf16
    short* vbfT    = kbf + (size_t)NPIX * CCH;             // [128][N] bf16
    short* cbf     = vbfT + (size_t)NPIX * CCH;            // [16][128] bf16

    proj_kernel<<<dim3(144, 3), 256, 0, stream>>>(
        q_img, k_img, v_img, labels, wq, bq, wk, bk, wv, bv,
        qbf, kbf, vbuf, vbfT, cpart, denpart);
    centersB_kernel<<<8, 256, 0, stream>>>(cpart, denpart, cbf);
    attn_part_kernel<<<dim3(144, KSPLIT), 256, 0, stream>>>(
        qbf, kbf, vbfT, cbf, labels, pc, part_o, part_l);
    mlp_chain_kernel<<<288, 256, 0, stream>>>(
        part_o, part_l, vbuf, w1a, b1a, w1b, b1b, w2a, b2a, w2b, b2b,
        (float*)d_out);
}